// Round 9
// baseline (647.350 us; speedup 1.0000x reference)
//
#include <hip/hip_runtime.h>
#include <math.h>

typedef unsigned int u32;
typedef unsigned short u16;
typedef __attribute__((ext_vector_type(8))) __bf16 bf16x8;   // 4 VGPRs, MFMA A/B operand
typedef __attribute__((ext_vector_type(4))) float f32x4;     // MFMA C/D operand

// Problem dims
#define B_     1024
#define T_     8
#define DIMM   512
#define DM1    511
#define NC     8192
#define M_     8192
#define NNZ_   65536
#define NEV    16384
#define K1_    768
#define N1_    4088
#define N1P    4096          // padded N for gemm1 MFMA

// Workspace layout (bytes)
#define WS_SCAL   0                         // [1]=base (gemm2 atomic)
#define WS_EVP    1024                      // event partials: 512 floats
#define WS_CORP   3072                      // corr partials: 256 floats
#define WS_FAHI   4096
#define WS_FALO   (WS_FAHI + 8388608)       // fa hi/lo [8192][512] bf16
#define WS_TCWHI  (WS_FALO + 8388608)
#define WS_TCWLO  (WS_TCWHI + 8388608)      // tcw hi/lo [8192][512] bf16
#define WS_FEATHI (WS_TCWLO + 8388608)
#define WS_FEATLO (WS_FEATHI + 1572864)     // features hi/lo [1024][768] bf16
#define WS_WTHI   (WS_FEATLO + 1572864)
#define WS_WTLO   (WS_WTHI + 6291456)       // final_W^T hi/lo [4096][768] bf16

// ---------------------------------------------------------------------------
__device__ __forceinline__ u16 f2bf(float x) {
    union { float f; u32 u; } v; v.f = x;
    u32 r = v.u + 0x7FFFu + ((v.u >> 16) & 1u);
    return (u16)(r >> 16);
}
__device__ __forceinline__ float bf2f(u16 h) {
    union { u32 u; float f; } v; v.u = ((u32)h) << 16;
    return v.f;
}

__device__ __forceinline__ float wave_reduce(float v) {
    v += __shfl_xor(v, 1, 64);
    v += __shfl_xor(v, 2, 64);
    v += __shfl_xor(v, 4, 64);
    v += __shfl_xor(v, 8, 64);
    v += __shfl_xor(v, 16, 64);
    v += __shfl_xor(v, 32, 64);
    return v;
}

#define GLOAD16(gp, lp) __builtin_amdgcn_global_load_lds(                      \
    (const u32 __attribute__((address_space(1)))*)(gp),                        \
    (u32 __attribute__((address_space(3)))*)(lp), 16, 0, 0)

// ---------------------------------------------------------------------------
// prep: tcw -> hi/lo [8192][512] (bias in col 511). 4 elems/thread,
// packed uint2 stores (was 2B/lane store-issue-bound).
// ---------------------------------------------------------------------------
__global__ void tcw_convert_kernel(const float* __restrict__ cw,
                                   const float* __restrict__ cwb,
                                   u16* __restrict__ th, u16* __restrict__ tl)
{
    int i4 = (blockIdx.x * 256 + threadIdx.x) * 4;   // 0 .. 8192*512, step 4
    int r = i4 >> 9, c = i4 & 511;                   // c in {0,4,...,508}
    float x[4];
#pragma unroll
    for (int q = 0; q < 4; q++)
        x[q] = (c + q < DM1) ? cw[(size_t)r * DM1 + c + q] : cwb[r];
    u32 h01, h23, l01, l23;
    {
        u16 h0 = f2bf(x[0]), h1 = f2bf(x[1]), h2 = f2bf(x[2]), h3 = f2bf(x[3]);
        u16 l0 = f2bf(x[0] - bf2f(h0)), l1 = f2bf(x[1] - bf2f(h1));
        u16 l2 = f2bf(x[2] - bf2f(h2)), l3 = f2bf(x[3] - bf2f(h3));
        h01 = (u32)h0 | ((u32)h1 << 16); h23 = (u32)h2 | ((u32)h3 << 16);
        l01 = (u32)l0 | ((u32)l1 << 16); l23 = (u32)l2 | ((u32)l3 << 16);
    }
    *(uint2*)&th[i4] = make_uint2(h01, h23);
    *(uint2*)&tl[i4] = make_uint2(l01, l23);
}

// prep: features -> hi/lo [1024][768], 4 elems/thread
__global__ void feat_convert_kernel(const float* __restrict__ A,
                                    u16* __restrict__ ah, u16* __restrict__ al)
{
    int i4 = (blockIdx.x * 256 + threadIdx.x) * 4;
    float4 v = *(const float4*)&A[i4];
    u16 h0 = f2bf(v.x), h1 = f2bf(v.y), h2 = f2bf(v.z), h3 = f2bf(v.w);
    u16 l0 = f2bf(v.x - bf2f(h0)), l1 = f2bf(v.y - bf2f(h1));
    u16 l2 = f2bf(v.z - bf2f(h2)), l3 = f2bf(v.w - bf2f(h3));
    *(uint2*)&ah[i4] = make_uint2((u32)h0 | ((u32)h1 << 16), (u32)h2 | ((u32)h3 << 16));
    *(uint2*)&al[i4] = make_uint2((u32)l0 | ((u32)l1 << 16), (u32)l2 | ((u32)l3 << 16));
}

// prep: final_W [768][4088] -> W^T hi/lo [4096][768] (rows 4088..4095 zero)
__global__ __launch_bounds__(256) void wt_convert_kernel(const float* __restrict__ W,
                                                         u16* __restrict__ wh,
                                                         u16* __restrict__ wl)
{
    __shared__ float tile[32][33];
    const int bx = blockIdx.x;           // n tile: 0..127
    const int by = blockIdx.y;           // k tile: 0..23
    const int tx = threadIdx.x & 31, ty = threadIdx.x >> 5;   // 32 x 8
#pragma unroll
    for (int i = 0; i < 4; i++) {
        int k = by * 32 + ty + i * 8;
        int n = bx * 32 + tx;
        tile[ty + i * 8][tx] = (n < N1_) ? W[(size_t)k * N1_ + n] : 0.f;
    }
    __syncthreads();
#pragma unroll
    for (int i = 0; i < 4; i++) {
        int n2 = bx * 32 + ty + i * 8;   // output row (< 4096)
        int k2 = by * 32 + tx;           // output col
        float x = tile[tx][ty + i * 8];  // = W[k2][n2]
        u16 h = f2bf(x);
        size_t o = (size_t)n2 * K1_ + k2;
        wh[o] = h;
        wl[o] = f2bf(x - bf2f(h));
    }
}

// ---------------------------------------------------------------------------
// GEMM1 split-bf16 MFMA, 64x128 tile, 512 blocks; fa[:,511]=1 folded into
// the n>=4088 epilogue lanes (no fill_ones launch).
// ---------------------------------------------------------------------------
__global__ __launch_bounds__(256) void gemm1_mfma_kernel(
    const u16* __restrict__ ah_g, const u16* __restrict__ al_g,  // feat hi/lo [1024][768]
    const u16* __restrict__ bh_g, const u16* __restrict__ bl_g,  // wt hi/lo [4096][768]
    const float* __restrict__ bias,
    u16* __restrict__ fh, u16* __restrict__ fl)                  // fa hi/lo out
{
    __shared__ __align__(16) u16 sAh[64 * 32];
    __shared__ __align__(16) u16 sAl[64 * 32];
    __shared__ __align__(16) u16 sBh[128 * 32];
    __shared__ __align__(16) u16 sBl[128 * 32];

    const int bm = blockIdx.y * 64, bn = blockIdx.x * 128;
    const int t = threadIdx.x;
    const int l = t & 63, w = t >> 6;
    const int wm = w >> 1, wn = w & 1;

    const int srow   = l >> 2;                      // 0..15
    const int schunk = (l & 3) ^ ((l >> 4) & 3);    // XOR key valid: wave row-bases %16==0

    f32x4 acc[2][4];
#pragma unroll
    for (int mf = 0; mf < 2; mf++)
#pragma unroll
        for (int nf = 0; nf < 4; nf++) acc[mf][nf] = (f32x4){0.f, 0.f, 0.f, 0.f};

    const int fr = l & 15, ks = l >> 4;

    for (int k0 = 0; k0 < K1_; k0 += 32) {
        {   // A tile 64x32: wave w stages rows [16w,16w+16)
            size_t goA = (size_t)(bm + w * 16 + srow) * K1_ + k0 + schunk * 8;
            u32 lo = (u32)(w * 16) * 32;
            GLOAD16(ah_g + goA, &sAh[lo]);
            GLOAD16(al_g + goA, &sAl[lo]);
        }
#pragma unroll
        for (int i = 0; i < 2; i++) {   // B tile 128x32: wave w stages rows [32w,32w+32)
            int r0 = w * 32 + i * 16;
            size_t goB = (size_t)(bn + r0 + srow) * K1_ + k0 + schunk * 8;
            u32 lo = (u32)r0 * 32;
            GLOAD16(bh_g + goB, &sBh[lo]);
            GLOAD16(bl_g + goB, &sBl[lo]);
        }
        __syncthreads();

        const bf16x8* pAh = (const bf16x8*)sAh;
        const bf16x8* pAl = (const bf16x8*)sAl;
        const bf16x8* pBh = (const bf16x8*)sBh;
        const bf16x8* pBl = (const bf16x8*)sBl;

        bf16x8 ah[2], al[2], bh[4], bl[4];
#pragma unroll
        for (int mf = 0; mf < 2; mf++) {
            int row = wm * 32 + mf * 16 + fr;
            int c = ks ^ ((row >> 2) & 3);
            ah[mf] = pAh[row * 4 + c];
            al[mf] = pAl[row * 4 + c];
        }
#pragma unroll
        for (int nf = 0; nf < 4; nf++) {
            int row = wn * 64 + nf * 16 + fr;
            int c = ks ^ ((row >> 2) & 3);
            bh[nf] = pBh[row * 4 + c];
            bl[nf] = pBl[row * 4 + c];
        }
#pragma unroll
        for (int mf = 0; mf < 2; mf++)
#pragma unroll
            for (int nf = 0; nf < 4; nf++) {
                acc[mf][nf] = __builtin_amdgcn_mfma_f32_16x16x32_bf16(ah[mf], bh[nf], acc[mf][nf], 0, 0, 0);
                acc[mf][nf] = __builtin_amdgcn_mfma_f32_16x16x32_bf16(ah[mf], bl[nf], acc[mf][nf], 0, 0, 0);
                acc[mf][nf] = __builtin_amdgcn_mfma_f32_16x16x32_bf16(al[mf], bh[nf], acc[mf][nf], 0, 0, 0);
            }
        __syncthreads();
    }

    // epilogue: + bias, split hi/lo, scatter into fa[(m*8+tt)*512+d];
    // n in [4088,4096) carries the ones column: fa[(m*8+(n-4088))*512+511] = 1
#pragma unroll
    for (int mf = 0; mf < 2; mf++) {
#pragma unroll
        for (int j = 0; j < 4; j++) {
            int m = bm + wm * 32 + mf * 16 + ks * 4 + j;
#pragma unroll
            for (int nf = 0; nf < 4; nf++) {
                int n = bn + wn * 64 + nf * 16 + fr;
                float x; int tt, d;
                if (n < N1_) {
                    x = acc[mf][nf][j] + bias[n];
                    tt = n / DM1;
                    d  = n - tt * DM1;
                } else {
                    x = 1.0f;            // ones column
                    tt = n - N1_;        // 0..7
                    d  = DM1;
                }
                u16 h = f2bf(x);
                size_t o = (size_t)(m * T_ + tt) * DIMM + d;
                fh[o] = h;
                fl[o] = f2bf(x - bf2f(h));
            }
        }
    }
}

// ---------------------------------------------------------------------------
// GEMM2 split-bf16 MFMA. Retile: block 128x256, 4 waves (2Mx2N), wave tile
// 64x128 — LDS reads/MFMA 0.33 -> 0.25 (r6 post-mortem: LDS-BW-bound:
// 16 b128/wave/Kstep * 8cy on shared CU LDS unit = 2.2x oversubscribed vs
// MFMA -> MfmaUtil ceiling 45%, observed 36.5%). A-frags register-resident,
// B-frags streamed. 2-barrier sync structure unchanged.
// ---------------------------------------------------------------------------
__global__ __launch_bounds__(256) void gemm2_kernel(
    const u16* __restrict__ fh, const u16* __restrict__ fl,
    const u16* __restrict__ th, const u16* __restrict__ tl,
    const float* __restrict__ defs,
    float* __restrict__ logits,
    float* __restrict__ scal)
{
    __shared__ __align__(16) u16 sAh[128 * 32];
    __shared__ __align__(16) u16 sAl[128 * 32];
    __shared__ __align__(16) u16 sBh[256 * 32];
    __shared__ __align__(16) u16 sBl[256 * 32];
    __shared__ float sdef[128];
    __shared__ float sred[4];

    const int bm = blockIdx.y * 128, bn = blockIdx.x * 256;
    const int t = threadIdx.x;
    const int l = t & 63, w = t >> 6;
    const int wm = w >> 1, wn = w & 1;          // 2x2 wave grid, wave tile 64x128

    if (t < 128) sdef[t] = exp2f(defs[bm + t]);

    const int srow   = l >> 2;
    const int schunk = (l & 3) ^ ((l >> 4) & 3);

    f32x4 acc[4][8];
#pragma unroll
    for (int mf = 0; mf < 4; mf++)
#pragma unroll
        for (int nf = 0; nf < 8; nf++) acc[mf][nf] = (f32x4){0.f, 0.f, 0.f, 0.f};

    const int fr = l & 15, ks = l >> 4;

    for (int k0 = 0; k0 < DIMM; k0 += 32) {
        // A 128x32 hi/lo: wave w stages rows [32w, 32w+32)
#pragma unroll
        for (int i = 0; i < 2; i++) {
            int r0 = w * 32 + i * 16;
            size_t goA = (size_t)(bm + r0 + srow) * DIMM + k0 + schunk * 8;
            u32 lo = (u32)r0 * 32;
            GLOAD16(fh + goA, &sAh[lo]);
            GLOAD16(fl + goA, &sAl[lo]);
        }
        // B 256x32 hi/lo: wave w stages rows [64w, 64w+64)
#pragma unroll
        for (int i = 0; i < 4; i++) {
            int r0 = w * 64 + i * 16;
            size_t goB = (size_t)(bn + r0 + srow) * DIMM + k0 + schunk * 8;
            u32 lo = (u32)r0 * 32;
            GLOAD16(th + goB, &sBh[lo]);
            GLOAD16(tl + goB, &sBl[lo]);
        }
        __syncthreads();

        const bf16x8* pAh = (const bf16x8*)sAh;
        const bf16x8* pAl = (const bf16x8*)sAl;
        const bf16x8* pBh = (const bf16x8*)sBh;
        const bf16x8* pBl = (const bf16x8*)sBl;

        bf16x8 ah[4], al[4];
#pragma unroll
        for (int mf = 0; mf < 4; mf++) {
            int row = wm * 64 + mf * 16 + fr;
            int c = ks ^ ((row >> 2) & 3);
            ah[mf] = pAh[row * 4 + c];
            al[mf] = pAl[row * 4 + c];
        }
#pragma unroll
        for (int nf = 0; nf < 8; nf++) {
            int row = wn * 128 + nf * 16 + fr;
            int c = ks ^ ((row >> 2) & 3);
            bf16x8 bh = pBh[row * 4 + c];
            bf16x8 bl = pBl[row * 4 + c];
#pragma unroll
            for (int mf = 0; mf < 4; mf++) {
                acc[mf][nf] = __builtin_amdgcn_mfma_f32_16x16x32_bf16(ah[mf], bh, acc[mf][nf], 0, 0, 0);
                acc[mf][nf] = __builtin_amdgcn_mfma_f32_16x16x32_bf16(ah[mf], bl, acc[mf][nf], 0, 0, 0);
                acc[mf][nf] = __builtin_amdgcn_mfma_f32_16x16x32_bf16(al[mf], bh, acc[mf][nf], 0, 0, 0);
            }
        }
        __syncthreads();
    }

    float basep = 0.f;
#pragma unroll
    for (int mf = 0; mf < 4; mf++) {
#pragma unroll
        for (int j = 0; j < 4; j++) {
            int lrow = wm * 64 + mf * 16 + ks * 4 + j;
            float ed = sdef[lrow];
            float* orow = &logits[(size_t)(bm + lrow) * NC + bn + wn * 128 + fr];
#pragma unroll
            for (int nf = 0; nf < 8; nf++) {
                float v = exp2f(acc[mf][nf][j]);
                orow[nf * 16] = v;
                basep += ed * v;
            }
        }
    }
    basep = wave_reduce(basep);
    if (l == 0) sred[w] = basep;
    __syncthreads();
    if (t == 0) atomicAdd(&scal[1], sred[0] + sred[1] + sred[2] + sred[3]);
}

// ---------------------------------------------------------------------------
// Small kernels
// ---------------------------------------------------------------------------
__global__ __launch_bounds__(256) void corr_kernel(
    const int* __restrict__ rows, const int* __restrict__ cols,
    const float* __restrict__ vals, const float* __restrict__ defs,
    const float* __restrict__ logits, float* __restrict__ corrpart)
{
    __shared__ float sw[4];
    int k = blockIdx.x * 256 + threadIdx.x;
    int r  = rows[k];
    int cc = cols[k];
    float lg = logits[(size_t)r * NC + cc];
    float c = lg * (exp2f(vals[k]) - exp2f(defs[r]));
    c = wave_reduce(c);
    int wid = threadIdx.x >> 6;
    if ((threadIdx.x & 63) == 0) sw[wid] = c;
    __syncthreads();
    if (threadIdx.x == 0) corrpart[blockIdx.x] = sw[0] + sw[1] + sw[2] + sw[3];
}

__global__ __launch_bounds__(256) void event_kernel(
    const int* __restrict__ ev,
    const u16* __restrict__ fh, const u16* __restrict__ fl,
    const u16* __restrict__ th, const u16* __restrict__ tl,
    float* __restrict__ evpart)
{
    __shared__ float sw[4];
    const int w = threadIdx.x >> 6, lane = threadIdx.x & 63;
    const int wg = blockIdx.x * 4 + w;           // 0..2047
    float s = 0.f;
#pragma unroll
    for (int e = 0; e < 8; e++) {
        int eid = wg * 8 + e;
        int r = ev[eid * 2 + 0];
        int c = ev[eid * 2 + 1];
        uint4 ahv = *(const uint4*)(fh + (size_t)r * DIMM + lane * 8);
        uint4 alv = *(const uint4*)(fl + (size_t)r * DIMM + lane * 8);
        uint4 bhv = *(const uint4*)(th + (size_t)c * DIMM + lane * 8);
        uint4 blv = *(const uint4*)(tl + (size_t)c * DIMM + lane * 8);
        const u32* ah = (const u32*)&ahv;
        const u32* al = (const u32*)&alv;
        const u32* bh = (const u32*)&bhv;
        const u32* bl = (const u32*)&blv;
#pragma unroll
        for (int q = 0; q < 4; q++) {
            float a0 = bf2f((u16)(ah[q] & 0xffff)) + bf2f((u16)(al[q] & 0xffff));
            float a1 = bf2f((u16)(ah[q] >> 16))    + bf2f((u16)(al[q] >> 16));
            float b0 = bf2f((u16)(bh[q] & 0xffff)) + bf2f((u16)(bl[q] & 0xffff));
            float b1 = bf2f((u16)(bh[q] >> 16))    + bf2f((u16)(bl[q] >> 16));
            s += a0 * b0 + a1 * b1;
        }
    }
    s = wave_reduce(s);
    if (lane == 0) sw[w] = s;
    __syncthreads();
    if (threadIdx.x == 0) evpart[blockIdx.x] = sw[0] + sw[1] + sw[2] + sw[3];
}

__global__ __launch_bounds__(256) void final_kernel(
    const int* __restrict__ mask, const float* __restrict__ scal,
    const float* __restrict__ evpart, const float* __restrict__ corrpart,
    float* __restrict__ out)
{
    __shared__ float swe[4], swc[4], swm[4];
    int t = threadIdx.x;
    float se = evpart[t] + evpart[t + 256];
    float sc = corrpart[t];
    float sm = 0.f;
    for (int i = t; i < B_; i += 256) sm += (mask[i] != 0) ? 1.f : 0.f;
    se = wave_reduce(se);
    sc = wave_reduce(sc);
    sm = wave_reduce(sm);
    int w = t >> 6;
    if ((t & 63) == 0) { swe[w] = se; swc[w] = sc; swm[w] = sm; }
    __syncthreads();
    if (t == 0) {
        float evs  = swe[0] + swe[1] + swe[2] + swe[3];
        float corr = swc[0] + swc[1] + swc[2] + swc[3];
        float nm   = swm[0] + swm[1] + swm[2] + swm[3];
        float base = scal[1];
        float exp_mean   = (base + corr) / ((float)M_ * (float)NC);
        float survival   = exp_mean * ((float)M_ / nm);
        float event_loss = -0.69314718055994530942f * evs / (nm * (float)NC);
        out[0] = event_loss + survival;
    }
}

// ---------------------------------------------------------------------------
extern "C" void kernel_launch(void* const* d_in, const int* in_sizes, int n_in,
                              void* d_out, int out_size, void* d_ws, size_t ws_size,
                              hipStream_t stream)
{
    const float* features = (const float*)d_in[0];
    const int*   mask     = (const int*)d_in[1];   // jax bool -> int32 (validated r2)
    const float* code_weight      = (const float*)d_in[2];
    const float* code_weight_bias = (const float*)d_in[3];
    const float* final_W = (const float*)d_in[4];
    const float* final_b = (const float*)d_in[5];
    const int*   sparse_rows = (const int*)d_in[6];
    const int*   sparse_cols = (const int*)d_in[7];
    const float* sparse_defaults = (const float*)d_in[8];
    const float* sparse_values   = (const float*)d_in[9];
    const int*   event_indices   = (const int*)d_in[10];

    float* out    = (float*)d_out;
    float* logits = out + 1;

    char* ws = (char*)d_ws;
    float* scal     = (float*)(ws + WS_SCAL);
    float* evpart   = (float*)(ws + WS_EVP);
    float* corrpart = (float*)(ws + WS_CORP);
    u16* fa_hi   = (u16*)(ws + WS_FAHI);
    u16* fa_lo   = (u16*)(ws + WS_FALO);
    u16* tcw_hi  = (u16*)(ws + WS_TCWHI);
    u16* tcw_lo  = (u16*)(ws + WS_TCWLO);
    u16* feat_hi = (u16*)(ws + WS_FEATHI);
    u16* feat_lo = (u16*)(ws + WS_FEATLO);
    u16* wt_hi   = (u16*)(ws + WS_WTHI);
    u16* wt_lo   = (u16*)(ws + WS_WTLO);

    hipMemsetAsync(scal, 0, 256, stream);

    tcw_convert_kernel<<<dim3((NC * DIMM) / 1024), 256, 0, stream>>>(
        code_weight, code_weight_bias, tcw_hi, tcw_lo);
    feat_convert_kernel<<<dim3((B_ * K1_) / 1024), 256, 0, stream>>>(
        features, feat_hi, feat_lo);
    wt_convert_kernel<<<dim3(N1P / 32, K1_ / 32), 256, 0, stream>>>(
        final_W, wt_hi, wt_lo);
    gemm1_mfma_kernel<<<dim3(N1P / 128, B_ / 64), 256, 0, stream>>>(
        feat_hi, feat_lo, wt_hi, wt_lo, final_b, fa_hi, fa_lo);
    gemm2_kernel<<<dim3(NC / 256, NC / 128), 256, 0, stream>>>(
        fa_hi, fa_lo, tcw_hi, tcw_lo, sparse_defaults, logits, scal);
    corr_kernel<<<dim3(NNZ_ / 256), 256, 0, stream>>>(sparse_rows, sparse_cols, sparse_values,
                                                      sparse_defaults, logits, corrpart);
    event_kernel<<<dim3(512), 256, 0, stream>>>(event_indices, fa_hi, fa_lo,
                                                tcw_hi, tcw_lo, evpart);
    final_kernel<<<dim3(1), 256, 0, stream>>>(mask, scal, evpart, corrpart, out);
}

// Round 11
// 582.228 us; speedup vs baseline: 1.1118x; 1.1118x over previous
//
#include <hip/hip_runtime.h>
#include <math.h>

typedef unsigned int u32;
typedef unsigned short u16;
typedef __attribute__((ext_vector_type(8))) __bf16 bf16x8;   // 4 VGPRs, MFMA A/B operand
typedef __attribute__((ext_vector_type(4))) float f32x4;     // MFMA C/D operand

// Problem dims
#define B_     1024
#define T_     8
#define DIMM   512
#define DM1    511
#define NC     8192
#define M_     8192
#define NNZ_   65536
#define NEV    16384
#define K1_    768
#define N1_    4088
#define N1P    4096          // padded N for gemm1 MFMA

// Workspace layout (bytes)
#define WS_SCAL   0                         // [1]=base (gemm2 atomic)
#define WS_EVP    1024                      // event partials: 512 floats
#define WS_CORP   3072                      // corr partials: 256 floats
#define WS_FAHI   4096
#define WS_FALO   (WS_FAHI + 8388608)       // fa hi/lo [8192][512] bf16
#define WS_TCWHI  (WS_FALO + 8388608)
#define WS_TCWLO  (WS_TCWHI + 8388608)      // tcw hi/lo [8192][512] bf16
#define WS_FEATHI (WS_TCWLO + 8388608)
#define WS_FEATLO (WS_FEATHI + 1572864)     // features hi/lo [1024][768] bf16
#define WS_WTHI   (WS_FEATLO + 1572864)
#define WS_WTLO   (WS_WTHI + 6291456)       // final_W^T hi/lo [4096][768] bf16

// ---------------------------------------------------------------------------
__device__ __forceinline__ u16 f2bf(float x) {
    union { float f; u32 u; } v; v.f = x;
    u32 r = v.u + 0x7FFFu + ((v.u >> 16) & 1u);
    return (u16)(r >> 16);
}
__device__ __forceinline__ float bf2f(u16 h) {
    union { u32 u; float f; } v; v.u = ((u32)h) << 16;
    return v.f;
}

__device__ __forceinline__ float wave_reduce(float v) {
    v += __shfl_xor(v, 1, 64);
    v += __shfl_xor(v, 2, 64);
    v += __shfl_xor(v, 4, 64);
    v += __shfl_xor(v, 8, 64);
    v += __shfl_xor(v, 16, 64);
    v += __shfl_xor(v, 32, 64);
    return v;
}

#define GLOAD16(gp, lp) __builtin_amdgcn_global_load_lds(                      \
    (const u32 __attribute__((address_space(1)))*)(gp),                        \
    (u32 __attribute__((address_space(3)))*)(lp), 16, 0, 0)

// ---------------------------------------------------------------------------
// prep_kernel (round-10 fusion: tcw_convert + feat_convert + wt_convert +
// scal zeroing in ONE dispatch; residual analysis suggests ~15-20us per
// launch — cut 9 launches to 5).
// Block ranges: [0,4096) tcw; [4096,4864) feat; [4864,7936) wt.
// ---------------------------------------------------------------------------
__global__ __launch_bounds__(256) void prep_kernel(
    const float* __restrict__ cw, const float* __restrict__ cwb,
    const float* __restrict__ feat, const float* __restrict__ W,
    u16* __restrict__ th, u16* __restrict__ tl,
    u16* __restrict__ ah, u16* __restrict__ al,
    u16* __restrict__ wh, u16* __restrict__ wl,
    float* __restrict__ scal)
{
    __shared__ float tile[32][33];
    const int b = blockIdx.x;
    if (b == 0 && threadIdx.x == 0) scal[1] = 0.f;   // zero base accumulator

    if (b < 4096) {
        // tcw -> hi/lo [8192][512] (bias in col 511), 4 elems/thread
        int i4 = (b * 256 + threadIdx.x) * 4;
        int r = i4 >> 9, c = i4 & 511;
        float x[4];
#pragma unroll
        for (int q = 0; q < 4; q++)
            x[q] = (c + q < DM1) ? cw[(size_t)r * DM1 + c + q] : cwb[r];
        u16 h0 = f2bf(x[0]), h1 = f2bf(x[1]), h2 = f2bf(x[2]), h3 = f2bf(x[3]);
        u16 l0 = f2bf(x[0] - bf2f(h0)), l1 = f2bf(x[1] - bf2f(h1));
        u16 l2 = f2bf(x[2] - bf2f(h2)), l3 = f2bf(x[3] - bf2f(h3));
        *(uint2*)&th[i4] = make_uint2((u32)h0 | ((u32)h1 << 16), (u32)h2 | ((u32)h3 << 16));
        *(uint2*)&tl[i4] = make_uint2((u32)l0 | ((u32)l1 << 16), (u32)l2 | ((u32)l3 << 16));
    } else if (b < 4864) {
        // features -> hi/lo [1024][768], 4 elems/thread
        int i4 = ((b - 4096) * 256 + threadIdx.x) * 4;
        float4 v = *(const float4*)&feat[i4];
        u16 h0 = f2bf(v.x), h1 = f2bf(v.y), h2 = f2bf(v.z), h3 = f2bf(v.w);
        u16 l0 = f2bf(v.x - bf2f(h0)), l1 = f2bf(v.y - bf2f(h1));
        u16 l2 = f2bf(v.z - bf2f(h2)), l3 = f2bf(v.w - bf2f(h3));
        *(uint2*)&ah[i4] = make_uint2((u32)h0 | ((u32)h1 << 16), (u32)h2 | ((u32)h3 << 16));
        *(uint2*)&al[i4] = make_uint2((u32)l0 | ((u32)l1 << 16), (u32)l2 | ((u32)l3 << 16));
    } else {
        // final_W [768][4088] -> W^T hi/lo [4096][768] (rows 4088..4095 zero)
        int bb = b - 4864;
        const int bx = bb & 127;            // n tile: 0..127
        const int by = bb >> 7;             // k tile: 0..23
        const int tx = threadIdx.x & 31, ty = threadIdx.x >> 5;   // 32 x 8
#pragma unroll
        for (int i = 0; i < 4; i++) {
            int k = by * 32 + ty + i * 8;
            int n = bx * 32 + tx;
            tile[ty + i * 8][tx] = (n < N1_) ? W[(size_t)k * N1_ + n] : 0.f;
        }
        __syncthreads();
#pragma unroll
        for (int i = 0; i < 4; i++) {
            int n2 = bx * 32 + ty + i * 8;   // output row (< 4096)
            int k2 = by * 32 + tx;           // output col
            float x = tile[tx][ty + i * 8];  // = W[k2][n2]
            u16 h = f2bf(x);
            size_t o = (size_t)n2 * K1_ + k2;
            wh[o] = h;
            wl[o] = f2bf(x - bf2f(h));
        }
    }
}

// ---------------------------------------------------------------------------
// GEMM1 split-bf16 MFMA, 64x128 tile, 512 blocks; fa[:,511]=1 folded into
// the n>=4088 epilogue lanes.
// ---------------------------------------------------------------------------
__global__ __launch_bounds__(256) void gemm1_mfma_kernel(
    const u16* __restrict__ ah_g, const u16* __restrict__ al_g,  // feat hi/lo [1024][768]
    const u16* __restrict__ bh_g, const u16* __restrict__ bl_g,  // wt hi/lo [4096][768]
    const float* __restrict__ bias,
    u16* __restrict__ fh, u16* __restrict__ fl)                  // fa hi/lo out
{
    __shared__ __align__(16) u16 sAh[64 * 32];
    __shared__ __align__(16) u16 sAl[64 * 32];
    __shared__ __align__(16) u16 sBh[128 * 32];
    __shared__ __align__(16) u16 sBl[128 * 32];

    const int bm = blockIdx.y * 64, bn = blockIdx.x * 128;
    const int t = threadIdx.x;
    const int l = t & 63, w = t >> 6;
    const int wm = w >> 1, wn = w & 1;

    const int srow   = l >> 2;                      // 0..15
    const int schunk = (l & 3) ^ ((l >> 4) & 3);    // XOR key valid: wave row-bases %16==0

    f32x4 acc[2][4];
#pragma unroll
    for (int mf = 0; mf < 2; mf++)
#pragma unroll
        for (int nf = 0; nf < 4; nf++) acc[mf][nf] = (f32x4){0.f, 0.f, 0.f, 0.f};

    const int fr = l & 15, ks = l >> 4;

    for (int k0 = 0; k0 < K1_; k0 += 32) {
        {   // A tile 64x32: wave w stages rows [16w,16w+16)
            size_t goA = (size_t)(bm + w * 16 + srow) * K1_ + k0 + schunk * 8;
            u32 lo = (u32)(w * 16) * 32;
            GLOAD16(ah_g + goA, &sAh[lo]);
            GLOAD16(al_g + goA, &sAl[lo]);
        }
#pragma unroll
        for (int i = 0; i < 2; i++) {   // B tile 128x32: wave w stages rows [32w,32w+32)
            int r0 = w * 32 + i * 16;
            size_t goB = (size_t)(bn + r0 + srow) * K1_ + k0 + schunk * 8;
            u32 lo = (u32)r0 * 32;
            GLOAD16(bh_g + goB, &sBh[lo]);
            GLOAD16(bl_g + goB, &sBl[lo]);
        }
        __syncthreads();

        const bf16x8* pAh = (const bf16x8*)sAh;
        const bf16x8* pAl = (const bf16x8*)sAl;
        const bf16x8* pBh = (const bf16x8*)sBh;
        const bf16x8* pBl = (const bf16x8*)sBl;

        bf16x8 ah[2], al[2], bh[4], bl[4];
#pragma unroll
        for (int mf = 0; mf < 2; mf++) {
            int row = wm * 32 + mf * 16 + fr;
            int c = ks ^ ((row >> 2) & 3);
            ah[mf] = pAh[row * 4 + c];
            al[mf] = pAl[row * 4 + c];
        }
#pragma unroll
        for (int nf = 0; nf < 4; nf++) {
            int row = wn * 64 + nf * 16 + fr;
            int c = ks ^ ((row >> 2) & 3);
            bh[nf] = pBh[row * 4 + c];
            bl[nf] = pBl[row * 4 + c];
        }
#pragma unroll
        for (int mf = 0; mf < 2; mf++)
#pragma unroll
            for (int nf = 0; nf < 4; nf++) {
                acc[mf][nf] = __builtin_amdgcn_mfma_f32_16x16x32_bf16(ah[mf], bh[nf], acc[mf][nf], 0, 0, 0);
                acc[mf][nf] = __builtin_amdgcn_mfma_f32_16x16x32_bf16(ah[mf], bl[nf], acc[mf][nf], 0, 0, 0);
                acc[mf][nf] = __builtin_amdgcn_mfma_f32_16x16x32_bf16(al[mf], bh[nf], acc[mf][nf], 0, 0, 0);
            }
        __syncthreads();
    }

    // epilogue: + bias, split hi/lo, scatter into fa[(m*8+tt)*512+d];
    // n in [4088,4096) carries the ones column
#pragma unroll
    for (int mf = 0; mf < 2; mf++) {
#pragma unroll
        for (int j = 0; j < 4; j++) {
            int m = bm + wm * 32 + mf * 16 + ks * 4 + j;
#pragma unroll
            for (int nf = 0; nf < 4; nf++) {
                int n = bn + wn * 64 + nf * 16 + fr;
                float x; int tt, d;
                if (n < N1_) {
                    x = acc[mf][nf][j] + bias[n];
                    tt = n / DM1;
                    d  = n - tt * DM1;
                } else {
                    x = 1.0f;            // ones column
                    tt = n - N1_;        // 0..7
                    d  = DM1;
                }
                u16 h = f2bf(x);
                size_t o = (size_t)(m * T_ + tt) * DIMM + d;
                fh[o] = h;
                fl[o] = f2bf(x - bf2f(h));
            }
        }
    }
}

// ---------------------------------------------------------------------------
// GEMM2 split-bf16 MFMA — REVERTED to the proven round-3/6 128x128 config
// (254us, MfmaUtil 36.5%). Round-9 post-mortem: 128x256 retile REGRESSED to
// 337us — VGPR 96->188 + LDS 33->49KB halved resident blocks/CU, killing the
// inter-wave overlap that hides the barrier drain (matches guide m105/m112:
// 128^2 is optimal for 2-barrier structures; bigger tiles need 8-phase).
// ---------------------------------------------------------------------------
__global__ __launch_bounds__(256) void gemm2_kernel(
    const u16* __restrict__ fh, const u16* __restrict__ fl,
    const u16* __restrict__ th, const u16* __restrict__ tl,
    const float* __restrict__ defs,
    float* __restrict__ logits,
    float* __restrict__ scal)
{
    __shared__ __align__(16) u16 sAh[128 * 32];
    __shared__ __align__(16) u16 sAl[128 * 32];
    __shared__ __align__(16) u16 sBh[128 * 32];
    __shared__ __align__(16) u16 sBl[128 * 32];
    __shared__ float sdef[128];
    __shared__ float sred[4];

    const int bm = blockIdx.y * 128, bn = blockIdx.x * 128;
    const int t = threadIdx.x;
    const int l = t & 63, w = t >> 6;
    const int wm = w >> 1, wn = w & 1;

    if (t < 128) sdef[t] = exp2f(defs[bm + t]);

    const int srow   = l >> 2;
    const int schunk = (l & 3) ^ ((l >> 4) & 3);

    f32x4 acc[4][4];
#pragma unroll
    for (int mf = 0; mf < 4; mf++)
#pragma unroll
        for (int nf = 0; nf < 4; nf++) acc[mf][nf] = (f32x4){0.f, 0.f, 0.f, 0.f};

    const int fr = l & 15, ks = l >> 4;

    for (int k0 = 0; k0 < DIMM; k0 += 32) {
#pragma unroll
        for (int i = 0; i < 2; i++) {
            int r0 = w * 32 + i * 16;
            size_t goA = (size_t)(bm + r0 + srow) * DIMM + k0 + schunk * 8;
            size_t goB = (size_t)(bn + r0 + srow) * DIMM + k0 + schunk * 8;
            u32 lo = (u32)r0 * 32;
            GLOAD16(fh + goA, &sAh[lo]);
            GLOAD16(fl + goA, &sAl[lo]);
            GLOAD16(th + goB, &sBh[lo]);
            GLOAD16(tl + goB, &sBl[lo]);
        }
        __syncthreads();

        const bf16x8* pAh = (const bf16x8*)sAh;
        const bf16x8* pAl = (const bf16x8*)sAl;
        const bf16x8* pBh = (const bf16x8*)sBh;
        const bf16x8* pBl = (const bf16x8*)sBl;

        bf16x8 ah[4], al[4], bh[4], bl[4];
#pragma unroll
        for (int mf = 0; mf < 4; mf++) {
            int row = wm * 64 + mf * 16 + fr;
            int c = ks ^ ((row >> 2) & 3);
            ah[mf] = pAh[row * 4 + c];
            al[mf] = pAl[row * 4 + c];
        }
#pragma unroll
        for (int nf = 0; nf < 4; nf++) {
            int row = wn * 64 + nf * 16 + fr;
            int c = ks ^ ((row >> 2) & 3);
            bh[nf] = pBh[row * 4 + c];
            bl[nf] = pBl[row * 4 + c];
        }
#pragma unroll
        for (int mf = 0; mf < 4; mf++)
#pragma unroll
            for (int nf = 0; nf < 4; nf++) {
                acc[mf][nf] = __builtin_amdgcn_mfma_f32_16x16x32_bf16(ah[mf], bh[nf], acc[mf][nf], 0, 0, 0);
                acc[mf][nf] = __builtin_amdgcn_mfma_f32_16x16x32_bf16(ah[mf], bl[nf], acc[mf][nf], 0, 0, 0);
                acc[mf][nf] = __builtin_amdgcn_mfma_f32_16x16x32_bf16(al[mf], bh[nf], acc[mf][nf], 0, 0, 0);
            }
        __syncthreads();
    }

    float basep = 0.f;
#pragma unroll
    for (int mf = 0; mf < 4; mf++) {
#pragma unroll
        for (int j = 0; j < 4; j++) {
            int lrow = wm * 64 + mf * 16 + ks * 4 + j;
            float ed = sdef[lrow];
            float* orow = &logits[(size_t)(bm + lrow) * NC + bn + wn * 64 + fr];
#pragma unroll
            for (int nf = 0; nf < 4; nf++) {
                float v = exp2f(acc[mf][nf][j]);
                orow[nf * 16] = v;
                basep += ed * v;
            }
        }
    }
    basep = wave_reduce(basep);
    if (l == 0) sred[w] = basep;
    __syncthreads();
    if (t == 0) atomicAdd(&scal[1], sred[0] + sred[1] + sred[2] + sred[3]);
}

// ---------------------------------------------------------------------------
// corr + event fused (round-10): blocks [0,256) corr, [256,768) event.
// ---------------------------------------------------------------------------
__global__ __launch_bounds__(256) void corr_event_kernel(
    const int* __restrict__ rows, const int* __restrict__ cols,
    const float* __restrict__ vals, const float* __restrict__ defs,
    const float* __restrict__ logits,
    const int* __restrict__ ev,
    const u16* __restrict__ fh, const u16* __restrict__ fl,
    const u16* __restrict__ th, const u16* __restrict__ tl,
    float* __restrict__ corrpart, float* __restrict__ evpart)
{
    __shared__ float sw[4];
    const int wv = threadIdx.x >> 6, lane = threadIdx.x & 63;

    if (blockIdx.x < 256) {
        int k = blockIdx.x * 256 + threadIdx.x;
        int r  = rows[k];
        int cc = cols[k];
        float lg = logits[(size_t)r * NC + cc];
        float c = lg * (exp2f(vals[k]) - exp2f(defs[r]));
        c = wave_reduce(c);
        if (lane == 0) sw[wv] = c;
        __syncthreads();
        if (threadIdx.x == 0) corrpart[blockIdx.x] = sw[0] + sw[1] + sw[2] + sw[3];
    } else {
        const int wg = (blockIdx.x - 256) * 4 + wv;   // 0..2047
        float s = 0.f;
#pragma unroll
        for (int e = 0; e < 8; e++) {
            int eid = wg * 8 + e;
            int r = ev[eid * 2 + 0];
            int c = ev[eid * 2 + 1];
            uint4 ahv = *(const uint4*)(fh + (size_t)r * DIMM + lane * 8);
            uint4 alv = *(const uint4*)(fl + (size_t)r * DIMM + lane * 8);
            uint4 bhv = *(const uint4*)(th + (size_t)c * DIMM + lane * 8);
            uint4 blv = *(const uint4*)(tl + (size_t)c * DIMM + lane * 8);
            const u32* ah = (const u32*)&ahv;
            const u32* al = (const u32*)&alv;
            const u32* bh = (const u32*)&bhv;
            const u32* bl = (const u32*)&blv;
#pragma unroll
            for (int q = 0; q < 4; q++) {
                float a0 = bf2f((u16)(ah[q] & 0xffff)) + bf2f((u16)(al[q] & 0xffff));
                float a1 = bf2f((u16)(ah[q] >> 16))    + bf2f((u16)(al[q] >> 16));
                float b0 = bf2f((u16)(bh[q] & 0xffff)) + bf2f((u16)(bl[q] & 0xffff));
                float b1 = bf2f((u16)(bh[q] >> 16))    + bf2f((u16)(bl[q] >> 16));
                s += a0 * b0 + a1 * b1;
            }
        }
        s = wave_reduce(s);
        if (lane == 0) sw[wv] = s;
        __syncthreads();
        if (threadIdx.x == 0) evpart[blockIdx.x - 256] = sw[0] + sw[1] + sw[2] + sw[3];
    }
}

// final: mask count + partial reduction + loss combine
__global__ __launch_bounds__(256) void final_kernel(
    const int* __restrict__ mask, const float* __restrict__ scal,
    const float* __restrict__ evpart, const float* __restrict__ corrpart,
    float* __restrict__ out)
{
    __shared__ float swe[4], swc[4], swm[4];
    int t = threadIdx.x;
    float se = evpart[t] + evpart[t + 256];
    float sc = corrpart[t];
    float sm = 0.f;
    for (int i = t; i < B_; i += 256) sm += (mask[i] != 0) ? 1.f : 0.f;
    se = wave_reduce(se);
    sc = wave_reduce(sc);
    sm = wave_reduce(sm);
    int w = t >> 6;
    if ((t & 63) == 0) { swe[w] = se; swc[w] = sc; swm[w] = sm; }
    __syncthreads();
    if (t == 0) {
        float evs  = swe[0] + swe[1] + swe[2] + swe[3];
        float corr = swc[0] + swc[1] + swc[2] + swc[3];
        float nm   = swm[0] + swm[1] + swm[2] + swm[3];
        float base = scal[1];
        float exp_mean   = (base + corr) / ((float)M_ * (float)NC);
        float survival   = exp_mean * ((float)M_ / nm);
        float event_loss = -0.69314718055994530942f * evs / (nm * (float)NC);
        out[0] = event_loss + survival;
    }
}

// ---------------------------------------------------------------------------
extern "C" void kernel_launch(void* const* d_in, const int* in_sizes, int n_in,
                              void* d_out, int out_size, void* d_ws, size_t ws_size,
                              hipStream_t stream)
{
    const float* features = (const float*)d_in[0];
    const int*   mask     = (const int*)d_in[1];   // jax bool -> int32 (validated r2)
    const float* code_weight      = (const float*)d_in[2];
    const float* code_weight_bias = (const float*)d_in[3];
    const float* final_W = (const float*)d_in[4];
    const float* final_b = (const float*)d_in[5];
    const int*   sparse_rows = (const int*)d_in[6];
    const int*   sparse_cols = (const int*)d_in[7];
    const float* sparse_defaults = (const float*)d_in[8];
    const float* sparse_values   = (const float*)d_in[9];
    const int*   event_indices   = (const int*)d_in[10];

    float* out    = (float*)d_out;
    float* logits = out + 1;

    char* ws = (char*)d_ws;
    float* scal     = (float*)(ws + WS_SCAL);
    float* evpart   = (float*)(ws + WS_EVP);
    float* corrpart = (float*)(ws + WS_CORP);
    u16* fa_hi   = (u16*)(ws + WS_FAHI);
    u16* fa_lo   = (u16*)(ws + WS_FALO);
    u16* tcw_hi  = (u16*)(ws + WS_TCWHI);
    u16* tcw_lo  = (u16*)(ws + WS_TCWLO);
    u16* feat_hi = (u16*)(ws + WS_FEATHI);
    u16* feat_lo = (u16*)(ws + WS_FEATLO);
    u16* wt_hi   = (u16*)(ws + WS_WTHI);
    u16* wt_lo   = (u16*)(ws + WS_WTLO);

    // 5 dispatches total (round-10: was 9 incl. memset)
    prep_kernel<<<dim3(7936), 256, 0, stream>>>(
        code_weight, code_weight_bias, features, final_W,
        tcw_hi, tcw_lo, feat_hi, feat_lo, wt_hi, wt_lo, scal);
    gemm1_mfma_kernel<<<dim3(N1P / 128, B_ / 64), 256, 0, stream>>>(
        feat_hi, feat_lo, wt_hi, wt_lo, final_b, fa_hi, fa_lo);
    gemm2_kernel<<<dim3(64, 64), 256, 0, stream>>>(
        fa_hi, fa_lo, tcw_hi, tcw_lo, sparse_defaults, logits, scal);
    corr_event_kernel<<<dim3(768), 256, 0, stream>>>(
        sparse_rows, sparse_cols, sparse_values, sparse_defaults, logits,
        event_indices, fa_hi, fa_lo, tcw_hi, tcw_lo, corrpart, evpart);
    final_kernel<<<dim3(1), 256, 0, stream>>>(mask, scal, evpart, corrpart, out);
}